// Round 1
// baseline (2070.143 us; speedup 1.0000x reference)
//
#include <hip/hip_runtime.h>
#include <math.h>

// Problem constants
constexpr int NB = 2, NL = 2048, ND = 1024, NH = 4, NDK = 256, NDV = 256;
constexpr int NCHK = 64;            // L / 32
constexpr int NBL = NB * NL;        // 4096
#define BLDSZ (NB * NL * ND)        // 4194304

// ---- static device scratch (avoids unknown ws_size; ~221 MB) ----
__device__ float g_qlin[BLDSZ];
__device__ float g_klin[BLDSZ];
__device__ float g_vlin[BLDSZ];
__device__ float g_q[BLDSZ];      // post conv+silu; overwritten in-place with l2-normalized qn
__device__ float g_k[BLDSZ];      // post conv+silu; overwritten in-place with kn
__device__ float g_v[BLDSZ];
__device__ float g_u[BLDSZ];      // (B,H,L,DV)
__device__ float g_w[BLDSZ];      // (B,H,L,DK)
__device__ float g_delta[BLDSZ];  // (B,L,H,DV)
__device__ float g_fs[BLDSZ];
__device__ float g_fl[BLDSZ];
__device__ float g_xw1[BLDSZ];    // x @ W1[:1024,:]
__device__ float g_omix[BLDSZ];
__device__ float g_beta[NBL * NH];
__device__ float g_stats[NBL * NH * 16];
__device__ float g_p[NBL * NH * 4];
__device__ float g_attn[NB * NH * NCHK * 32 * 32];  // incl_lower(qn kn^T) per chunk

__device__ __forceinline__ float sigmoidf(float x) { return 1.f / (1.f + expf(-x)); }

// ================= SGEMM: C[4096,1024] = A[4096,1024] * B[1024,1024] =================
// 128x128 block tile, BK=16, 256 threads, 8x8 per thread.
__global__ __launch_bounds__(256) void sgemm_kernel(const float* __restrict__ Aext,
                                                    const float* __restrict__ Bw,
                                                    float* __restrict__ Cext, int sel) {
  __shared__ float As[16][132];
  __shared__ float Bs[16][132];
  const float* A = (sel == 4) ? g_omix : Aext;
  float* C;
  if (sel == 0) C = g_qlin;
  else if (sel == 1) C = g_klin;
  else if (sel == 2) C = g_vlin;
  else if (sel == 3) C = g_xw1;
  else C = Cext;

  const int t = threadIdx.x;
  const int tx = t & 15, ty = t >> 4;
  const int n0 = blockIdx.x * 128, m0 = blockIdx.y * 128;
  float acc[8][8];
#pragma unroll
  for (int i = 0; i < 8; ++i)
#pragma unroll
    for (int j = 0; j < 8; ++j) acc[i][j] = 0.f;

  for (int k0 = 0; k0 < 1024; k0 += 16) {
    // load A tile 128x16 (512 float4s, 2/thread)
#pragma unroll
    for (int i = 0; i < 2; ++i) {
      int j = t + i * 256;
      int m = j >> 2, k4 = (j & 3) << 2;
      float4 av = *(const float4*)&A[(size_t)(m0 + m) * 1024 + k0 + k4];
      As[k4 + 0][m] = av.x; As[k4 + 1][m] = av.y; As[k4 + 2][m] = av.z; As[k4 + 3][m] = av.w;
    }
    // load B tile 16x128
#pragma unroll
    for (int i = 0; i < 2; ++i) {
      int j = t + i * 256;
      int kk = j >> 5, n4 = (j & 31) << 2;
      *(float4*)&Bs[kk][n4] = *(const float4*)&Bw[(size_t)(k0 + kk) * 1024 + n0 + n4];
    }
    __syncthreads();
#pragma unroll
    for (int kk = 0; kk < 16; ++kk) {
      float4 a0 = *(const float4*)&As[kk][ty * 8];
      float4 a1 = *(const float4*)&As[kk][ty * 8 + 4];
      float4 b0 = *(const float4*)&Bs[kk][tx * 4];
      float4 b1 = *(const float4*)&Bs[kk][64 + tx * 4];
      float av[8] = {a0.x, a0.y, a0.z, a0.w, a1.x, a1.y, a1.z, a1.w};
      float bv[8] = {b0.x, b0.y, b0.z, b0.w, b1.x, b1.y, b1.z, b1.w};
#pragma unroll
      for (int i = 0; i < 8; ++i)
#pragma unroll
        for (int j = 0; j < 8; ++j) acc[i][j] += av[i] * bv[j];
    }
    __syncthreads();
  }
#pragma unroll
  for (int i = 0; i < 8; ++i) {
    size_t row = (size_t)(m0 + ty * 8 + i) * 1024 + n0;
    float4 r0, r1;
    r0.x = acc[i][0]; r0.y = acc[i][1]; r0.z = acc[i][2]; r0.w = acc[i][3];
    r1.x = acc[i][4]; r1.y = acc[i][5]; r1.z = acc[i][6]; r1.w = acc[i][7];
    *(float4*)&C[row + tx * 4] = r0;
    *(float4*)&C[row + 64 + tx * 4] = r1;
  }
}

// ================= causal depthwise conv (K=4) + SiLU =================
__global__ __launch_bounds__(256) void conv_silu_kernel(const float* __restrict__ cw, int sel) {
  const float* in = (sel == 0) ? g_qlin : (sel == 1) ? g_klin : g_vlin;
  float* out = (sel == 0) ? g_q : (sel == 1) ? g_k : g_v;
  int idx = blockIdx.x * 256 + threadIdx.x;
  int c = idx & (ND - 1);
  int bl = idx >> 10;
  int l = bl & (NL - 1);
  float w0 = cw[c * 4 + 0], w1 = cw[c * 4 + 1], w2 = cw[c * 4 + 2], w3 = cw[c * 4 + 3];
  float acc = w3 * in[(size_t)bl * ND + c];
  if (l >= 1) acc += w2 * in[(size_t)(bl - 1) * ND + c];
  if (l >= 2) acc += w1 * in[(size_t)(bl - 2) * ND + c];
  if (l >= 3) acc += w0 * in[(size_t)(bl - 3) * ND + c];
  out[idx] = acc * sigmoidf(acc);
}

// ================= beta = sigmoid(x @ Wb) =================
__global__ __launch_bounds__(256) void beta_kernel(const float* __restrict__ x,
                                                   const float* __restrict__ Wb) {
  int bl = blockIdx.x;
  int h = threadIdx.x >> 6, lane = threadIdx.x & 63;
  const float* xr = x + (size_t)bl * ND;
  float acc = 0.f;
  for (int d = lane; d < ND; d += 64) acc += xr[d] * Wb[d * 4 + h];
#pragma unroll
  for (int off = 32; off; off >>= 1) acc += __shfl_xor(acc, off);
  if (lane == 0) g_beta[bl * 4 + h] = sigmoidf(acc);
}

// ================= FIR short (K=5) =================
__global__ __launch_bounds__(256) void fir_short_kernel(const float* __restrict__ filt) {
  int idx = blockIdx.x * 256 + threadIdx.x;
  int c = idx & (ND - 1);
  int bl = idx >> 10;
  int l = bl & (NL - 1);
  const float* fp = filt + c * 5;
  float acc = 0.f;
#pragma unroll
  for (int tap = 0; tap < 5; ++tap) {
    int ls = l + tap - 4;
    if (ls >= 0) acc += fp[tap] * g_v[(size_t)(bl + tap - 4) * ND + c];
  }
  g_fs[idx] = acc;
}

// ================= FIR long (K=64), filter staged in LDS =================
__global__ __launch_bounds__(256) void fir_long_kernel(const float* __restrict__ filt) {
  __shared__ float ft[64][257];
  int blk = blockIdx.x;                 // ((b*4 + cbk)*32 + lb)
  int lb = blk & 31, cbk = (blk >> 5) & 3, b = blk >> 7;
  int t = threadIdx.x;
  const float* fb = filt + (size_t)cbk * 256 * 64;
#pragma unroll 4
  for (int i = 0; i < 64; ++i) {
    int j = t + i * 256;
    ft[j & 63][j >> 6] = fb[j];
  }
  __syncthreads();
  int c = cbk * 256 + t;
  int l0 = lb * 64;
  for (int li = 0; li < 64; ++li) {
    int l = l0 + li;
    float acc = 0.f;
    int tmin = (l >= 63) ? 0 : 63 - l;
    for (int tap = tmin; tap < 64; ++tap)
      acc += ft[tap][t] * g_v[(size_t)(b * NL + l + tap - 63) * ND + c];
    g_fl[(size_t)(b * NL + l) * ND + c] = acc;
  }
}

// ================= delta-rule chunk prep =================
// per (b,h,chunk): l2norm q,k (in-place to g_q/g_k); attn=incl_lower(qn kn^T);
// A=strict_lower(kb kn^T); T=(I+A)^-1; w=T@kb; u=T@(v*beta)
__global__ __launch_bounds__(256) void delta_prep_kernel() {
  __shared__ float X[32][260];
  __shared__ float Y[32][260];
  __shared__ float Am[32][33];
  __shared__ float Tm[32][33];
  __shared__ float bet[32];
  int blk = blockIdx.x;                  // ((b*4+h)*64 + n)
  int n = blk & 63, h = (blk >> 6) & 3, b = blk >> 8;
  int t = threadIdx.x;
  size_t rowbase = (size_t)(b * NL + n * 32);

  // load q->X, k->Y
#pragma unroll
  for (int i = 0; i < 8; ++i) {
    int j = t + i * 256;
    int r = j >> 6, d4 = (j & 63) << 2;
    size_t gi = (rowbase + r) * ND + h * 256 + d4;
    *(float4*)&X[r][d4] = *(const float4*)&g_q[gi];
    *(float4*)&Y[r][d4] = *(const float4*)&g_k[gi];
  }
  if (t < 32) bet[t] = g_beta[(rowbase + t) * 4 + h];
  __syncthreads();

  // row l2norm (8 lanes per row), write back LDS + global
  {
    int wv = t >> 6, lane = t & 63;
    int r = wv * 8 + (lane >> 3), sub = lane & 7;
    float sq = 0.f, sk = 0.f;
#pragma unroll
    for (int m4 = 0; m4 < 8; ++m4) {
      float4 a = *(const float4*)&X[r][sub * 32 + m4 * 4];
      float4 bb = *(const float4*)&Y[r][sub * 32 + m4 * 4];
      sq += a.x * a.x + a.y * a.y + a.z * a.z + a.w * a.w;
      sk += bb.x * bb.x + bb.y * bb.y + bb.z * bb.z + bb.w * bb.w;
    }
    sq += __shfl_xor(sq, 1); sq += __shfl_xor(sq, 2); sq += __shfl_xor(sq, 4);
    sk += __shfl_xor(sk, 1); sk += __shfl_xor(sk, 2); sk += __shfl_xor(sk, 4);
    float rq = rsqrtf(sq + 1e-6f), rk = rsqrtf(sk + 1e-6f);
#pragma unroll
    for (int m4 = 0; m4 < 8; ++m4) {
      size_t gi = (rowbase + r) * ND + h * 256 + sub * 32 + m4 * 4;
      float4 a = *(const float4*)&X[r][sub * 32 + m4 * 4];
      a.x *= rq; a.y *= rq; a.z *= rq; a.w *= rq;
      *(float4*)&X[r][sub * 32 + m4 * 4] = a;
      *(float4*)&g_q[gi] = a;
      float4 bb = *(const float4*)&Y[r][sub * 32 + m4 * 4];
      bb.x *= rk; bb.y *= rk; bb.z *= rk; bb.w *= rk;
      *(float4*)&Y[r][sub * 32 + m4 * 4] = bb;
      *(float4*)&g_k[gi] = bb;
    }
  }
  __syncthreads();

  // attn_pre = incl_lower(qn kn^T)
#pragma unroll
  for (int i = 0; i < 4; ++i) {
    int pr = t + i * 256;
    int r = pr >> 5, s = pr & 31;
    float acc = 0.f;
    if (s <= r) {
#pragma unroll 16
      for (int d4 = 0; d4 < 64; ++d4) {
        float4 a = *(const float4*)&X[r][d4 * 4];
        float4 bb = *(const float4*)&Y[s][d4 * 4];
        acc += a.x * bb.x + a.y * bb.y + a.z * bb.z + a.w * bb.w;
      }
    }
    g_attn[((size_t)(b * 4 + h) * 64 + n) * 1024 + r * 32 + s] = acc;
  }
  __syncthreads();

  // X <- k_beta
#pragma unroll
  for (int i = 0; i < 8; ++i) {
    int j = t + i * 256;
    int r = j >> 6, d4 = (j & 63) << 2;
    float be = bet[r];
    float4 bb = *(const float4*)&Y[r][d4];
    bb.x *= be; bb.y *= be; bb.z *= be; bb.w *= be;
    *(float4*)&X[r][d4] = bb;
  }
  __syncthreads();

  // A = strict_lower(kb kn^T)
#pragma unroll
  for (int i = 0; i < 4; ++i) {
    int pr = t + i * 256;
    int r = pr >> 5, s = pr & 31;
    float acc = 0.f;
    if (s < r) {
#pragma unroll 16
      for (int d4 = 0; d4 < 64; ++d4) {
        float4 a = *(const float4*)&X[r][d4 * 4];
        float4 bb = *(const float4*)&Y[s][d4 * 4];
        acc += a.x * bb.x + a.y * bb.y + a.z * bb.z + a.w * bb.w;
      }
    }
    Am[r][s] = acc;
  }
  __syncthreads();

  // T = (I+A)^-1 via forward substitution (lane j owns column j)
  if (t < 32) {
    int j = t;
    for (int i = 0; i < 32; ++i) {
      float a = (i == j) ? 1.f : 0.f;
      for (int m = j; m < i; ++m) a -= Am[i][m] * Tm[m][j];
      Tm[i][j] = a;
    }
  }
  __syncthreads();

  // w = T @ kb  (column sweep, thread t owns d-column t); also load vb into Y
  {
    float acc[32];
#pragma unroll
    for (int r = 0; r < 32; ++r) acc[r] = 0.f;
#pragma unroll
    for (int m = 0; m < 32; ++m) {
      float xv = X[m][t];
#pragma unroll
      for (int r = m; r < 32; ++r) acc[r] += Tm[r][m] * xv;
    }
#pragma unroll
    for (int r = 0; r < 32; ++r)
      g_w[((size_t)(b * 4 + h) * NL + n * 32 + r) * 256 + t] = acc[r];
  }
#pragma unroll
  for (int i = 0; i < 8; ++i) {
    int j = t + i * 256;
    int r = j >> 6, d4 = (j & 63) << 2;
    size_t gi = (rowbase + r) * ND + h * 256 + d4;
    float be = bet[r];
    float4 vv = *(const float4*)&g_v[gi];
    vv.x *= be; vv.y *= be; vv.z *= be; vv.w *= be;
    *(float4*)&Y[r][d4] = vv;
  }
  __syncthreads();

  // u = T @ vb
  {
    float acc[32];
#pragma unroll
    for (int r = 0; r < 32; ++r) acc[r] = 0.f;
#pragma unroll
    for (int m = 0; m < 32; ++m) {
      float yv = Y[m][t];
#pragma unroll
      for (int r = m; r < 32; ++r) acc[r] += Tm[r][m] * yv;
    }
#pragma unroll
    for (int r = 0; r < 32; ++r)
      g_u[((size_t)(b * 4 + h) * NL + n * 32 + r) * 256 + t] = acc[r];
  }
}

// ================= delta-rule sequential scan =================
// block = (b,h, dv-block of 16 cols). S kept transposed in LDS: St[c][dk].
__global__ __launch_bounds__(256) void delta_scan_kernel() {
  __shared__ float St[16][260];
  __shared__ float Wc[32][260];
  __shared__ float Qc[32][260];
  __shared__ float Kc[32][260];
  __shared__ float Ut[32][20];
  __shared__ float At[32][36];
  int blk = blockIdx.x;            // bh*16 + cb
  int cb = blk & 15, bh = blk >> 4;
  int b = bh >> 2, h = bh & 3;
  int c0 = cb * 16;
  int t = threadIdx.x;
  for (int i = t; i < 16 * 260; i += 256) (&St[0][0])[i] = 0.f;
  const int rr = t >> 3;            // 0..31
  const int cp = (t & 7) * 2;       // 0,2,..,14
  __syncthreads();

  for (int n = 0; n < 64; ++n) {
    size_t qkbase = (size_t)(b * NL + n * 32) * ND + h * 256;
    size_t uwbase = ((size_t)bh * NL + n * 32) * 256;
    // stage w,q,k chunks + u slice + attn
#pragma unroll
    for (int i = 0; i < 8; ++i) {
      int j = t + i * 256;
      int r = j >> 6, d4 = (j & 63) << 2;
      *(float4*)&Wc[r][d4] = *(const float4*)&g_w[uwbase + r * 256 + d4];
      *(float4*)&Qc[r][d4] = *(const float4*)&g_q[qkbase + (size_t)r * ND + d4];
      *(float4*)&Kc[r][d4] = *(const float4*)&g_k[qkbase + (size_t)r * ND + d4];
    }
    if (t < 128) {
      int r = t >> 2, cq = (t & 3) * 4;
      *(float4*)&Ut[r][cq] = *(const float4*)&g_u[uwbase + r * 256 + c0 + cq];
    }
    {
      int r = t >> 3, s4 = (t & 7) * 4;
      *(float4*)&At[r][s4] = *(const float4*)&g_attn[((size_t)bh * 64 + n) * 1024 + r * 32 + s4];
    }
    __syncthreads();

    // fused: wu = (w @ S)[rr][cp..cp+1], o = (q @ S)[rr][cp..cp+1]
    float au0 = Ut[rr][cp], au1 = Ut[rr][cp + 1];
    float o0 = 0.f, o1 = 0.f, wu0 = 0.f, wu1 = 0.f;
#pragma unroll 8
    for (int d4 = 0; d4 < 64; ++d4) {
      float4 wv = *(const float4*)&Wc[rr][d4 * 4];
      float4 qv = *(const float4*)&Qc[rr][d4 * 4];
      float4 s0v = *(const float4*)&St[cp][d4 * 4];
      float4 s1v = *(const float4*)&St[cp + 1][d4 * 4];
      wu0 += wv.x * s0v.x + wv.y * s0v.y + wv.z * s0v.z + wv.w * s0v.w;
      wu1 += wv.x * s1v.x + wv.y * s1v.y + wv.z * s1v.z + wv.w * s1v.w;
      o0 += qv.x * s0v.x + qv.y * s0v.y + qv.z * s0v.z + qv.w * s0v.w;
      o1 += qv.x * s1v.x + qv.y * s1v.y + qv.z * s1v.z + qv.w * s1v.w;
    }
    Ut[rr][cp] = au0 - wu0;
    Ut[rr][cp + 1] = au1 - wu1;
    __syncthreads();

    // o += attn_local @ u_t ; write delta
#pragma unroll 8
    for (int m = 0; m < 32; ++m) {
      float a = At[rr][m];
      o0 += a * Ut[m][cp];
      o1 += a * Ut[m][cp + 1];
    }
    size_t oidx = (size_t)(b * NL + n * 32 + rr) * ND + h * 256 + c0 + cp;
    g_delta[oidx] = o0;
    g_delta[oidx + 1] = o1;

    // S += k^T @ u_t   (thread t owns dk-column t)
    float acc[16];
#pragma unroll
    for (int c = 0; c < 16; ++c) acc[c] = 0.f;
#pragma unroll 4
    for (int r2 = 0; r2 < 32; ++r2) {
      float kv = Kc[r2][t];
#pragma unroll
      for (int c = 0; c < 16; ++c) acc[c] += kv * Ut[r2][c];
    }
#pragma unroll
    for (int c = 0; c < 16; ++c) St[c][t] += acc[c];
    __syncthreads();
  }
}

// ================= per-branch stats =================
__global__ __launch_bounds__(64) void stats_kernel() {
  int g = blockIdx.x;               // bl*4 + h
  int h = g & 3, bl = g >> 2;
  int lane = threadIdx.x;
  size_t base = (size_t)bl * ND + h * 256 + lane * 4;
#pragma unroll
  for (int br = 0; br < 4; ++br) {
    const float* p = (br == 0) ? g_fs : (br == 1) ? g_fl : (br == 2) ? g_delta : g_v;
    float4 x4 = *(const float4*)&p[base];
    float s = x4.x + x4.y + x4.z + x4.w;
    float s2 = x4.x * x4.x + x4.y * x4.y + x4.z * x4.z + x4.w * x4.w;
    float sa = fabsf(x4.x) + fabsf(x4.y) + fabsf(x4.z) + fabsf(x4.w);
#pragma unroll
    for (int off = 32; off; off >>= 1) {
      s += __shfl_xor(s, off);
      s2 += __shfl_xor(s2, off);
      sa += __shfl_xor(sa, off);
    }
    if (lane == 0) {
      float mean = s * (1.f / 256.f);
      float4 o;
      o.x = mean;
      o.y = s2 * (1.f / 256.f) - mean * mean;
      o.z = sa * (1.f / 256.f);
      o.w = sqrtf(s2);
      *(float4*)&g_stats[(size_t)g * 16 + br * 4] = o;
    }
  }
}

// ================= gate MLP tail + softmax/floor =================
__global__ __launch_bounds__(256) void gate_kernel(const float* __restrict__ W1,
                                                   const float* __restrict__ b1,
                                                   const float* __restrict__ W2,
                                                   const float* __restrict__ b2,
                                                   const float* __restrict__ log_temp,
                                                   const float* __restrict__ base_bias,
                                                   const float* __restrict__ crl) {
  __shared__ float st[4][16];
  __shared__ float red[4][4];
  int bl = blockIdx.x, t = threadIdx.x;
  if (t < 64) (&st[0][0])[t] = g_stats[(size_t)bl * 64 + t];
  __syncthreads();
  const float* W1s = W1 + 1024 * 1024;
  for (int h = 0; h < 4; ++h) {
    float sv[16];
#pragma unroll
    for (int s = 0; s < 16; ++s) sv[s] = st[h][s];
    float a0 = 0.f, a1 = 0.f, a2 = 0.f, a3 = 0.f;
    for (int j = t; j < 1024; j += 256) {
      float val = g_xw1[(size_t)bl * 1024 + j] + b1[j];
#pragma unroll
      for (int s = 0; s < 16; ++s) val += sv[s] * W1s[s * 1024 + j];
      float gg = 0.5f * val * (1.f + erff(val * 0.70710678118654752f));
      float4 w2 = *(const float4*)&W2[j * 4];
      a0 += gg * w2.x; a1 += gg * w2.y; a2 += gg * w2.z; a3 += gg * w2.w;
    }
#pragma unroll
    for (int off = 32; off; off >>= 1) {
      a0 += __shfl_xor(a0, off); a1 += __shfl_xor(a1, off);
      a2 += __shfl_xor(a2, off); a3 += __shfl_xor(a3, off);
    }
    int wv = t >> 6, lane = t & 63;
    if (lane == 0) { red[wv][0] = a0; red[wv][1] = a1; red[wv][2] = a2; red[wv][3] = a3; }
    __syncthreads();
    if (t == 0) {
      float lg[4];
#pragma unroll
      for (int m = 0; m < 4; ++m)
        lg[m] = red[0][m] + red[1][m] + red[2][m] + red[3][m] + b2[m] + base_bias[h * 4 + m];
      float lt = log_temp[h];
      float sp = (lt > 20.f) ? lt : log1pf(expf(lt));
      float inv = 1.f / (sp + 1e-4f);
      float z0 = lg[0] * inv, z1 = lg[1] * inv, z2 = lg[2] * inv, z3 = lg[3] * inv;
      float mx = fmaxf(fmaxf(z0, z1), fmaxf(z2, z3));
      float e0 = expf(z0 - mx), e1 = expf(z1 - mx), e2 = expf(z2 - mx), e3 = expf(z3 - mx);
      float si = 1.f / (e0 + e1 + e2 + e3);
      float p0 = e0 * si, p1 = e1 * si, p2 = e2 * si, p3 = e3 * si;
      p0 = fmaxf(p0, 0.05f); p1 = fmaxf(p1, 0.05f);
      float s2i = 1.f / (p0 + p1 + p2 + p3);
      p0 *= s2i; p1 *= s2i; p2 *= s2i; p3 *= s2i;
      p0 += 0.5f * sigmoidf(crl[h]);   // fold conv-residual into f_short coeff
      float4 pv; pv.x = p0; pv.y = p1; pv.z = p2; pv.w = p3;
      *(float4*)&g_p[((size_t)bl * 4 + h) * 4] = pv;
    }
    __syncthreads();
  }
}

// ================= mix 4 branches + RMSNorm =================
__global__ __launch_bounds__(256) void mix_rms_kernel(const float* __restrict__ rms_w) {
  int bl = blockIdx.x;
  int h = threadIdx.x >> 6, lane = threadIdx.x & 63;
  const float* pp = &g_p[((size_t)bl * 4 + h) * 4];
  float p0 = pp[0], p1 = pp[1], p2 = pp[2], p3 = pp[3];
  size_t base = (size_t)bl * ND + h * 256 + lane * 4;
  float4 a = *(const float4*)&g_fs[base];
  float4 bb = *(const float4*)&g_fl[base];
  float4 c = *(const float4*)&g_delta[base];
  float4 d = *(const float4*)&g_v[base];
  float o0 = p0 * a.x + p1 * bb.x + p2 * c.x + p3 * d.x;
  float o1 = p0 * a.y + p1 * bb.y + p2 * c.y + p3 * d.y;
  float o2 = p0 * a.z + p1 * bb.z + p2 * c.z + p3 * d.z;
  float o3 = p0 * a.w + p1 * bb.w + p2 * c.w + p3 * d.w;
  float s2 = o0 * o0 + o1 * o1 + o2 * o2 + o3 * o3;
#pragma unroll
  for (int off = 32; off; off >>= 1) s2 += __shfl_xor(s2, off);
  float rms = rsqrtf(s2 * (1.f / 256.f) + 1e-5f);
  float4 w4 = *(const float4*)&rms_w[lane * 4];
  float4 o;
  o.x = o0 * rms * w4.x; o.y = o1 * rms * w4.y; o.z = o2 * rms * w4.z; o.w = o3 * rms * w4.w;
  *(float4*)&g_omix[base] = o;
}

extern "C" void kernel_launch(void* const* d_in, const int* in_sizes, int n_in,
                              void* d_out, int out_size, void* d_ws, size_t ws_size,
                              hipStream_t stream) {
  const float* x = (const float*)d_in[0];
  const float* Wq = (const float*)d_in[1];
  const float* Wk = (const float*)d_in[2];
  const float* Wv = (const float*)d_in[3];
  const float* Wb = (const float*)d_in[4];
  const float* cq = (const float*)d_in[5];
  const float* ck = (const float*)d_in[6];
  const float* cv = (const float*)d_in[7];
  const float* firl = (const float*)d_in[8];
  const float* firs = (const float*)d_in[9];
  const float* W1 = (const float*)d_in[10];
  const float* b1 = (const float*)d_in[11];
  const float* W2 = (const float*)d_in[12];
  const float* b2 = (const float*)d_in[13];
  const float* ltp = (const float*)d_in[14];
  const float* bbs = (const float*)d_in[15];
  const float* crl = (const float*)d_in[16];
  const float* rw = (const float*)d_in[17];
  const float* Wo = (const float*)d_in[18];
  float* out = (float*)d_out;

  dim3 gemm_grid(8, 32), blk(256);
  sgemm_kernel<<<gemm_grid, blk, 0, stream>>>(x, Wq, nullptr, 0);
  sgemm_kernel<<<gemm_grid, blk, 0, stream>>>(x, Wk, nullptr, 1);
  sgemm_kernel<<<gemm_grid, blk, 0, stream>>>(x, Wv, nullptr, 2);
  conv_silu_kernel<<<BLDSZ / 256, blk, 0, stream>>>(cq, 0);
  conv_silu_kernel<<<BLDSZ / 256, blk, 0, stream>>>(ck, 1);
  conv_silu_kernel<<<BLDSZ / 256, blk, 0, stream>>>(cv, 2);
  beta_kernel<<<NBL, blk, 0, stream>>>(x, Wb);
  sgemm_kernel<<<gemm_grid, blk, 0, stream>>>(x, W1, nullptr, 3);  // x @ W1[:1024,:]
  delta_prep_kernel<<<NB * NH * NCHK, blk, 0, stream>>>();
  delta_scan_kernel<<<NB * NH * 16, blk, 0, stream>>>();
  fir_short_kernel<<<BLDSZ / 256, blk, 0, stream>>>(firs);
  fir_long_kernel<<<256, blk, 0, stream>>>(firl);
  stats_kernel<<<NBL * NH, dim3(64), 0, stream>>>();
  gate_kernel<<<NBL, blk, 0, stream>>>(W1, b1, W2, b2, ltp, bbs, crl);
  mix_rms_kernel<<<NBL, blk, 0, stream>>>(rw);
  sgemm_kernel<<<gemm_grid, blk, 0, stream>>>(nullptr, Wo, out, 4);
}

// Round 2
// 1995.382 us; speedup vs baseline: 1.0375x; 1.0375x over previous
//
#include <hip/hip_runtime.h>
#include <math.h>

// Problem constants
constexpr int NB = 2, NL = 2048, ND = 1024, NH = 4;
constexpr int NCHK = 64;            // L / 32
constexpr int NBL = NB * NL;        // 4096
#define BLDSZ (NB * NL * ND)        // 4194304

// ---- static device scratch ----
__device__ float g_qlin[BLDSZ];
__device__ float g_klin[BLDSZ];
__device__ float g_vlin[BLDSZ];
__device__ float g_q[BLDSZ];      // post conv+silu (fp32, prep input)
__device__ float g_k[BLDSZ];
__device__ float g_v[BLDSZ];
__device__ float g_delta[BLDSZ];  // (B,L,H,DV)
__device__ float g_fs[BLDSZ];
__device__ float g_fl[BLDSZ];
__device__ float g_xw1[BLDSZ];    // x @ W1[:1024,:]
__device__ float g_omix[BLDSZ];
__device__ float g_beta[NBL * NH];
__device__ float g_stats[NBL * NH * 16];
__device__ float g_p[NBL * NH * 4];

// ---- bf16 operand tensors for the MFMA scan (ushort = bf16 bits) ----
// chunk linear index cblk = bh*64 + n  (bh = b*4+h)
__device__ unsigned short g_qb[8 * 64 * 32 * 256];    // (cblk, row, dk) row-major
__device__ unsigned short g_wb[8 * 64 * 32 * 256];    // (cblk, row, dk)
__device__ unsigned short g_ktb[8 * 64 * 256 * 32];   // (cblk, dk, row)   k^T
__device__ unsigned short g_utb[8 * 64 * 256 * 32];   // (cblk, dv, row)   u^T
__device__ unsigned short g_attnb[8 * 64 * 32 * 32];  // (cblk, r, s)

__device__ __forceinline__ float sigmoidf(float x) { return 1.f / (1.f + expf(-x)); }

__device__ __forceinline__ unsigned short f2bf(float f) {
  union { float f; unsigned int u; } v; v.f = f;
  unsigned int r = v.u + 0x7FFFu + ((v.u >> 16) & 1u);   // RNE
  return (unsigned short)(r >> 16);
}
__device__ __forceinline__ float bf2f(unsigned int bits16) {
  union { unsigned int u; float f; } v; v.u = bits16 << 16; return v.f;
}
__device__ __forceinline__ unsigned int packbf(float a, float b) {
  return (unsigned int)f2bf(a) | ((unsigned int)f2bf(b) << 16);
}

typedef __attribute__((ext_vector_type(8))) short short8v;   // 8 bf16 (4 VGPR)
typedef __attribute__((ext_vector_type(16))) float f32x16;   // MFMA 32x32 accum

// ================= SGEMM: C[4096,1024] = A[4096,1024] * B[1024,1024] =================
__global__ __launch_bounds__(256) void sgemm_kernel(const float* __restrict__ Aext,
                                                    const float* __restrict__ Bw,
                                                    float* __restrict__ Cext, int sel) {
  __shared__ float As[16][132];
  __shared__ float Bs[16][132];
  const float* A = (sel == 4) ? g_omix : Aext;
  float* C;
  if (sel == 0) C = g_qlin;
  else if (sel == 1) C = g_klin;
  else if (sel == 2) C = g_vlin;
  else if (sel == 3) C = g_xw1;
  else C = Cext;

  const int t = threadIdx.x;
  const int tx = t & 15, ty = t >> 4;
  const int n0 = blockIdx.x * 128, m0 = blockIdx.y * 128;
  float acc[8][8];
#pragma unroll
  for (int i = 0; i < 8; ++i)
#pragma unroll
    for (int j = 0; j < 8; ++j) acc[i][j] = 0.f;

  for (int k0 = 0; k0 < 1024; k0 += 16) {
#pragma unroll
    for (int i = 0; i < 2; ++i) {
      int j = t + i * 256;
      int m = j >> 2, k4 = (j & 3) << 2;
      float4 av = *(const float4*)&A[(size_t)(m0 + m) * 1024 + k0 + k4];
      As[k4 + 0][m] = av.x; As[k4 + 1][m] = av.y; As[k4 + 2][m] = av.z; As[k4 + 3][m] = av.w;
    }
#pragma unroll
    for (int i = 0; i < 2; ++i) {
      int j = t + i * 256;
      int kk = j >> 5, n4 = (j & 31) << 2;
      *(float4*)&Bs[kk][n4] = *(const float4*)&Bw[(size_t)(k0 + kk) * 1024 + n0 + n4];
    }
    __syncthreads();
#pragma unroll
    for (int kk = 0; kk < 16; ++kk) {
      float4 a0 = *(const float4*)&As[kk][ty * 8];
      float4 a1 = *(const float4*)&As[kk][ty * 8 + 4];
      float4 b0 = *(const float4*)&Bs[kk][tx * 4];
      float4 b1 = *(const float4*)&Bs[kk][64 + tx * 4];
      float av[8] = {a0.x, a0.y, a0.z, a0.w, a1.x, a1.y, a1.z, a1.w};
      float bv[8] = {b0.x, b0.y, b0.z, b0.w, b1.x, b1.y, b1.z, b1.w};
#pragma unroll
      for (int i = 0; i < 8; ++i)
#pragma unroll
        for (int j = 0; j < 8; ++j) acc[i][j] += av[i] * bv[j];
    }
    __syncthreads();
  }
#pragma unroll
  for (int i = 0; i < 8; ++i) {
    size_t row = (size_t)(m0 + ty * 8 + i) * 1024 + n0;
    float4 r0, r1;
    r0.x = acc[i][0]; r0.y = acc[i][1]; r0.z = acc[i][2]; r0.w = acc[i][3];
    r1.x = acc[i][4]; r1.y = acc[i][5]; r1.z = acc[i][6]; r1.w = acc[i][7];
    *(float4*)&C[row + tx * 4] = r0;
    *(float4*)&C[row + 64 + tx * 4] = r1;
  }
}

// ================= causal depthwise conv (K=4) + SiLU =================
__global__ __launch_bounds__(256) void conv_silu_kernel(const float* __restrict__ cw, int sel) {
  const float* in = (sel == 0) ? g_qlin : (sel == 1) ? g_klin : g_vlin;
  float* out = (sel == 0) ? g_q : (sel == 1) ? g_k : g_v;
  int idx = blockIdx.x * 256 + threadIdx.x;
  int c = idx & (ND - 1);
  int bl = idx >> 10;
  int l = bl & (NL - 1);
  float w0 = cw[c * 4 + 0], w1 = cw[c * 4 + 1], w2 = cw[c * 4 + 2], w3 = cw[c * 4 + 3];
  float acc = w3 * in[(size_t)bl * ND + c];
  if (l >= 1) acc += w2 * in[(size_t)(bl - 1) * ND + c];
  if (l >= 2) acc += w1 * in[(size_t)(bl - 2) * ND + c];
  if (l >= 3) acc += w0 * in[(size_t)(bl - 3) * ND + c];
  out[idx] = acc * sigmoidf(acc);
}

// ================= beta = sigmoid(x @ Wb) =================
__global__ __launch_bounds__(256) void beta_kernel(const float* __restrict__ x,
                                                   const float* __restrict__ Wb) {
  int bl = blockIdx.x;
  int h = threadIdx.x >> 6, lane = threadIdx.x & 63;
  const float* xr = x + (size_t)bl * ND;
  float acc = 0.f;
  for (int d = lane; d < ND; d += 64) acc += xr[d] * Wb[d * 4 + h];
#pragma unroll
  for (int off = 32; off; off >>= 1) acc += __shfl_xor(acc, off);
  if (lane == 0) g_beta[bl * 4 + h] = sigmoidf(acc);
}

// ================= FIR short (K=5) =================
__global__ __launch_bounds__(256) void fir_short_kernel(const float* __restrict__ filt) {
  int idx = blockIdx.x * 256 + threadIdx.x;
  int c = idx & (ND - 1);
  int bl = idx >> 10;
  int l = bl & (NL - 1);
  const float* fp = filt + c * 5;
  float acc = 0.f;
#pragma unroll
  for (int tap = 0; tap < 5; ++tap) {
    int ls = l + tap - 4;
    if (ls >= 0) acc += fp[tap] * g_v[(size_t)(bl + tap - 4) * ND + c];
  }
  g_fs[idx] = acc;
}

// ================= FIR long (K=64) =================
__global__ __launch_bounds__(256) void fir_long_kernel(const float* __restrict__ filt) {
  __shared__ float ft[64][257];
  int blk = blockIdx.x;                 // ((b*4 + cbk)*32 + lb)
  int lb = blk & 31, cbk = (blk >> 5) & 3, b = blk >> 7;
  int t = threadIdx.x;
  const float* fb = filt + (size_t)cbk * 256 * 64;
#pragma unroll 4
  for (int i = 0; i < 64; ++i) {
    int j = t + i * 256;
    ft[j & 63][j >> 6] = fb[j];
  }
  __syncthreads();
  int c = cbk * 256 + t;
  int l0 = lb * 64;
  for (int li = 0; li < 64; ++li) {
    int l = l0 + li;
    float acc = 0.f;
    int tmin = (l >= 63) ? 0 : 63 - l;
    for (int tap = tmin; tap < 64; ++tap)
      acc += ft[tap][t] * g_v[(size_t)(b * NL + l + tap - 63) * ND + c];
    g_fl[(size_t)(b * NL + l) * ND + c] = acc;
  }
}

// ================= delta-rule chunk prep =================
// per (b,h,chunk): l2norm q,k; attn=incl_lower(qn kn^T) -> bf16;
// A=strict_lower(kb kn^T); T=(I+A)^-1; w=T@kb -> bf16 row-major;
// u=T@(v*beta) -> bf16 transposed; qn -> bf16 row-major; kn -> bf16 transposed.
__global__ __launch_bounds__(256) void delta_prep_kernel() {
  __shared__ float X[32][260];
  __shared__ float Y[32][260];
  __shared__ float Am[32][33];
  __shared__ float Tm[32][33];
  __shared__ float bet[32];
  int blk = blockIdx.x;                  // cblk = (b*4+h)*64 + n
  int n = blk & 63, h = (blk >> 6) & 3, b = blk >> 8;
  int t = threadIdx.x;
  size_t rowbase = (size_t)(b * NL + n * 32);

  // load q->X, k->Y
#pragma unroll
  for (int i = 0; i < 8; ++i) {
    int j = t + i * 256;
    int r = j >> 6, d4 = (j & 63) << 2;
    size_t gi = (rowbase + r) * ND + h * 256 + d4;
    *(float4*)&X[r][d4] = *(const float4*)&g_q[gi];
    *(float4*)&Y[r][d4] = *(const float4*)&g_k[gi];
  }
  if (t < 32) bet[t] = g_beta[(rowbase + t) * 4 + h];
  __syncthreads();

  // row l2norm (8 lanes per row), LDS only
  {
    int wv = t >> 6, lane = t & 63;
    int r = wv * 8 + (lane >> 3), sub = lane & 7;
    float sq = 0.f, sk = 0.f;
#pragma unroll
    for (int m4 = 0; m4 < 8; ++m4) {
      float4 a = *(const float4*)&X[r][sub * 32 + m4 * 4];
      float4 bb = *(const float4*)&Y[r][sub * 32 + m4 * 4];
      sq += a.x * a.x + a.y * a.y + a.z * a.z + a.w * a.w;
      sk += bb.x * bb.x + bb.y * bb.y + bb.z * bb.z + bb.w * bb.w;
    }
    sq += __shfl_xor(sq, 1); sq += __shfl_xor(sq, 2); sq += __shfl_xor(sq, 4);
    sk += __shfl_xor(sk, 1); sk += __shfl_xor(sk, 2); sk += __shfl_xor(sk, 4);
    float rq = rsqrtf(sq + 1e-6f), rk = rsqrtf(sk + 1e-6f);
#pragma unroll
    for (int m4 = 0; m4 < 8; ++m4) {
      float4 a = *(const float4*)&X[r][sub * 32 + m4 * 4];
      a.x *= rq; a.y *= rq; a.z *= rq; a.w *= rq;
      *(float4*)&X[r][sub * 32 + m4 * 4] = a;
      float4 bb = *(const float4*)&Y[r][sub * 32 + m4 * 4];
      bb.x *= rk; bb.y *= rk; bb.z *= rk; bb.w *= rk;
      *(float4*)&Y[r][sub * 32 + m4 * 4] = bb;
    }
  }
  __syncthreads();

  // attn = incl_lower(qn kn^T) -> bf16
#pragma unroll
  for (int i = 0; i < 4; ++i) {
    int pr = t + i * 256;
    int r = pr >> 5, s = pr & 31;
    float acc = 0.f;
    if (s <= r) {
#pragma unroll 16
      for (int d4 = 0; d4 < 64; ++d4) {
        float4 a = *(const float4*)&X[r][d4 * 4];
        float4 bb = *(const float4*)&Y[s][d4 * 4];
        acc += a.x * bb.x + a.y * bb.y + a.z * bb.z + a.w * bb.w;
      }
    }
    g_attnb[(size_t)blk * 1024 + r * 32 + s] = f2bf(acc);
  }

  // qn -> g_qb (row-major, coalesced row sweep); kn -> g_ktb (transposed, packed per thread)
  {
#pragma unroll 8
    for (int r = 0; r < 32; ++r)
      g_qb[((size_t)blk * 32 + r) * 256 + t] = f2bf(X[r][t]);
#pragma unroll
    for (int r8 = 0; r8 < 4; ++r8) {
      uint4 v;
      v.x = packbf(Y[r8 * 8 + 0][t], Y[r8 * 8 + 1][t]);
      v.y = packbf(Y[r8 * 8 + 2][t], Y[r8 * 8 + 3][t]);
      v.z = packbf(Y[r8 * 8 + 4][t], Y[r8 * 8 + 5][t]);
      v.w = packbf(Y[r8 * 8 + 6][t], Y[r8 * 8 + 7][t]);
      *(uint4*)&g_ktb[((size_t)blk * 256 + t) * 32 + r8 * 8] = v;
    }
  }
  __syncthreads();

  // X <- k_beta
#pragma unroll
  for (int i = 0; i < 8; ++i) {
    int j = t + i * 256;
    int r = j >> 6, d4 = (j & 63) << 2;
    float be = bet[r];
    float4 bb = *(const float4*)&Y[r][d4];
    bb.x *= be; bb.y *= be; bb.z *= be; bb.w *= be;
    *(float4*)&X[r][d4] = bb;
  }
  __syncthreads();

  // A = strict_lower(kb kn^T)
#pragma unroll
  for (int i = 0; i < 4; ++i) {
    int pr = t + i * 256;
    int r = pr >> 5, s = pr & 31;
    float acc = 0.f;
    if (s < r) {
#pragma unroll 16
      for (int d4 = 0; d4 < 64; ++d4) {
        float4 a = *(const float4*)&X[r][d4 * 4];
        float4 bb = *(const float4*)&Y[s][d4 * 4];
        acc += a.x * bb.x + a.y * bb.y + a.z * bb.z + a.w * bb.w;
      }
    }
    Am[r][s] = acc;
  }
  __syncthreads();

  // T = (I+A)^-1 forward substitution (lane j owns column j)
  if (t < 32) {
    int j = t;
    for (int i = 0; i < 32; ++i) {
      float a = (i == j) ? 1.f : 0.f;
      for (int m = j; m < i; ++m) a -= Am[i][m] * Tm[m][j];
      Tm[i][j] = a;
    }
  }
  __syncthreads();

  // w = T @ kb (thread t owns dk-column t) -> g_wb row-major bf16
  {
    float acc[32];
#pragma unroll
    for (int r = 0; r < 32; ++r) acc[r] = 0.f;
#pragma unroll
    for (int m = 0; m < 32; ++m) {
      float xv = X[m][t];
#pragma unroll
      for (int r = m; r < 32; ++r) acc[r] += Tm[r][m] * xv;
    }
#pragma unroll 8
    for (int r = 0; r < 32; ++r)
      g_wb[((size_t)blk * 32 + r) * 256 + t] = f2bf(acc[r]);
  }
  // Y <- v*beta
#pragma unroll
  for (int i = 0; i < 8; ++i) {
    int j = t + i * 256;
    int r = j >> 6, d4 = (j & 63) << 2;
    size_t gi = (rowbase + r) * ND + h * 256 + d4;
    float be = bet[r];
    float4 vv = *(const float4*)&g_v[gi];
    vv.x *= be; vv.y *= be; vv.z *= be; vv.w *= be;
    *(float4*)&Y[r][d4] = vv;
  }
  __syncthreads();

  // u = T @ vb (thread t owns dv-column t) -> g_utb transposed bf16
  {
    float acc[32];
#pragma unroll
    for (int r = 0; r < 32; ++r) acc[r] = 0.f;
#pragma unroll
    for (int m = 0; m < 32; ++m) {
      float yv = Y[m][t];
#pragma unroll
      for (int r = m; r < 32; ++r) acc[r] += Tm[r][m] * yv;
    }
#pragma unroll
    for (int r8 = 0; r8 < 4; ++r8) {
      uint4 v;
      v.x = packbf(acc[r8 * 8 + 0], acc[r8 * 8 + 1]);
      v.y = packbf(acc[r8 * 8 + 2], acc[r8 * 8 + 3]);
      v.z = packbf(acc[r8 * 8 + 4], acc[r8 * 8 + 5]);
      v.w = packbf(acc[r8 * 8 + 6], acc[r8 * 8 + 7]);
      *(uint4*)&g_utb[((size_t)blk * 256 + t) * 32 + r8 * 8] = v;
    }
  }
}

// ================= delta-rule sequential scan — bf16 MFMA =================
// grid: 32 blocks = bh(8) * dv-quarter(4); block: 128 thr = 2 waves; wave owns 32 dv cols.
// Wave keeps its S slice (256dk x 32dv) in fp32 MFMA accumulators across all 64 chunks.
__global__ __launch_bounds__(128, 1) void delta_scan_mfma() {
  __shared__ unsigned short sW[32][264];       // w rows x dk (A-frags)
  __shared__ unsigned short sQ[32][264];       // q rows x dk
  __shared__ unsigned short sKt[256][40];      // k^T dk x rows (A-frags for S update)
  __shared__ unsigned short sU[64][40];        // u^T dv-slice x rows
  __shared__ unsigned short sA[32][40];        // attn r x s
  __shared__ unsigned short sSt[2][32][40];    // per-wave S^T scratch (dv x dk32)
  __shared__ unsigned short sUt[2][32][40];    // per-wave u_t^T (dv x rows)

  const int blk = blockIdx.x;
  const int qtr = blk & 3, bh = blk >> 2;
  const int b = bh >> 2, h = bh & 3;
  const int t = threadIdx.x;
  const int wv = t >> 6, lane = t & 63;
  const int l31 = lane & 31, lhi = lane >> 5;   // lhi: 0/1 (k-group)
  const int clocal = wv * 32 + l31;             // 0..63 within block dv slice
  const int cglob = qtr * 64 + clocal;          // dv within head

  f32x16 Sacc[8];
#pragma unroll
  for (int st = 0; st < 8; ++st)
#pragma unroll
    for (int e = 0; e < 16; ++e) Sacc[st][e] = 0.f;

  for (int n = 0; n < 64; ++n) {
    const size_t cblk = (size_t)bh * 64 + n;
    __syncthreads();   // protect LDS from previous iteration's readers
    // ---- stage chunk operands (all contiguous in global) ----
#pragma unroll
    for (int i = 0; i < 8; ++i) {
      int j = t + i * 128;                   // 0..1023
      int r = j >> 5, c8 = (j & 31) << 3;    // w/q: 32 rows x 256
      *(uint4*)&sW[r][c8] = *(const uint4*)&g_wb[cblk * 8192 + r * 256 + c8];
      *(uint4*)&sQ[r][c8] = *(const uint4*)&g_qb[cblk * 8192 + r * 256 + c8];
      int dk = j >> 2, k8 = (j & 3) << 3;    // kt: 256 x 32
      *(uint4*)&sKt[dk][k8] = *(const uint4*)&g_ktb[cblk * 8192 + dk * 32 + k8];
    }
#pragma unroll
    for (int i = 0; i < 2; ++i) {
      int j = t + i * 128;                   // 0..255
      int dv = j >> 2, k8 = (j & 3) << 3;
      *(uint4*)&sU[dv][k8] = *(const uint4*)&g_utb[cblk * 8192 + (qtr * 64 + dv) * 32 + k8];
    }
    {
      int r = t >> 2, k8 = (t & 3) << 3;
      *(uint4*)&sA[r][k8] = *(const uint4*)&g_attnb[cblk * 1024 + r * 32 + k8];
    }
    __syncthreads();

    // ---- phase 1: wu = w@S, oo = q@S (contract over dk via per-st S^T export) ----
    f32x16 wu, oo;
#pragma unroll
    for (int e = 0; e < 16; ++e) { wu[e] = 0.f; oo[e] = 0.f; }

#pragma unroll
    for (int st = 0; st < 8; ++st) {
      // export S^T block st: C layout col=l31(dv), row_dk = (reg&3)+8*(reg>>2)+4*lhi
#pragma unroll
      for (int g = 0; g < 4; ++g) {
        int r0 = 8 * g + 4 * lhi;
        uint2 pw;
        pw.x = packbf(Sacc[st][4 * g + 0], Sacc[st][4 * g + 1]);
        pw.y = packbf(Sacc[st][4 * g + 2], Sacc[st][4 * g + 3]);
        *(uint2*)&sSt[wv][l31][r0] = pw;
      }
#pragma unroll
      for (int kbi = 0; kbi < 2; ++kbi) {
        int ko = st * 32 + kbi * 16 + lhi * 8;
        short8v wa = *(const short8v*)&sW[l31][ko];
        short8v qa = *(const short8v*)&sQ[l31][ko];
        short8v sb = *(const short8v*)&sSt[wv][l31][kbi * 16 + lhi * 8];
        wu = __builtin_amdgcn_mfma_f32_32x32x16_bf16(wa, sb, wu, 0, 0, 0);
        oo = __builtin_amdgcn_mfma_f32_32x32x16_bf16(qa, sb, oo, 0, 0, 0);
      }
    }

    // ---- u_t = u - w@S  (bf16 to wave-private scratch) ----
#pragma unroll
    for (int g = 0; g < 4; ++g) {
      int r0 = 8 * g + 4 * lhi;
      uint2 uu = *(const uint2*)&sU[clocal][r0];
      float u0 = bf2f(uu.x & 0xffffu), u1 = bf2f(uu.x >> 16);
      float u2 = bf2f(uu.y & 0xffffu), u3 = bf2f(uu.y >> 16);
      uint2 pw;
      pw.x = packbf(u0 - wu[4 * g + 0], u1 - wu[4 * g + 1]);
      pw.y = packbf(u2 - wu[4 * g + 2], u3 - wu[4 * g + 3]);
      *(uint2*)&sUt[wv][l31][r0] = pw;
    }

    // ---- oo += attn @ u_t ; S += k^T @ u_t ----
    short8v ba0 = *(const short8v*)&sUt[wv][l31][lhi * 8];
    short8v ba1 = *(const short8v*)&sUt[wv][l31][16 + lhi * 8];
    {
      short8v aa0 = *(const short8v*)&sA[l31][lhi * 8];
      short8v aa1 = *(const short8v*)&sA[l31][16 + lhi * 8];
      oo = __builtin_amdgcn_mfma_f32_32x32x16_bf16(aa0, ba0, oo, 0, 0, 0);
      oo = __builtin_amdgcn_mfma_f32_32x32x16_bf16(aa1, ba1, oo, 0, 0, 0);
    }
#pragma unroll
    for (int st = 0; st < 8; ++st) {
      short8v ka0 = *(const short8v*)&sKt[st * 32 + l31][lhi * 8];
      short8v ka1 = *(const short8v*)&sKt[st * 32 + l31][16 + lhi * 8];
      Sacc[st] = __builtin_amdgcn_mfma_f32_32x32x16_bf16(ka0, ba0, Sacc[st], 0, 0, 0);
      Sacc[st] = __builtin_amdgcn_mfma_f32_32x32x16_bf16(ka1, ba1, Sacc[st], 0, 0, 0);
    }

    // ---- write delta (fp32) ----
#pragma unroll
    for (int g = 0; g < 4; ++g) {
      int r0 = 8 * g + 4 * lhi;
#pragma unroll
      for (int i = 0; i < 4; ++i) {
        int row = n * 32 + r0 + i;
        g_delta[((size_t)(b * NL + row)) * ND + h * 256 + cglob] = oo[4 * g + i];
      }
    }
  }
}

// ================= per-branch stats =================
__global__ __launch_bounds__(64) void stats_kernel() {
  int g = blockIdx.x;               // bl*4 + h
  int h = g & 3, bl = g >> 2;
  int lane = threadIdx.x;
  size_t base = (size_t)bl * ND + h * 256 + lane * 4;
#pragma unroll
  for (int br = 0; br < 4; ++br) {
    const float* p = (br == 0) ? g_fs : (br == 1) ? g_fl : (br == 2) ? g_delta : g_v;
    float4 x4 = *(const float4*)&p[base];
    float s = x4.x + x4.y + x4.z + x4.w;
    float s2 = x4.x * x4.x + x4.y * x4.y + x4.z * x4.z + x4.w * x4.w;
    float sa = fabsf(x4.x) + fabsf(x4.y) + fabsf(x4.z) + fabsf(x4.w);
#pragma unroll
    for (int off = 32; off; off >>= 1) {
      s += __shfl_xor(s, off);
      s2 += __shfl_xor(s2, off);
      sa += __shfl_xor(sa, off);
    }
    if (lane == 0) {
      float mean = s * (1.f / 256.f);
      float4 o;
      o.x = mean;
      o.y = s2 * (1.f / 256.f) - mean * mean;
      o.z = sa * (1.f / 256.f);
      o.w = sqrtf(s2);
      *(float4*)&g_stats[(size_t)g * 16 + br * 4] = o;
    }
  }
}

// ================= gate MLP tail + softmax/floor =================
__global__ __launch_bounds__(256) void gate_kernel(const float* __restrict__ W1,
                                                   const float* __restrict__ b1,
                                                   const float* __restrict__ W2,
                                                   const float* __restrict__ b2,
                                                   const float* __restrict__ log_temp,
                                                   const float* __restrict__ base_bias,
                                                   const float* __restrict__ crl) {
  __shared__ float st[4][16];
  __shared__ float red[4][4];
  int bl = blockIdx.x, t = threadIdx.x;
  if (t < 64) (&st[0][0])[t] = g_stats[(size_t)bl * 64 + t];
  __syncthreads();
  const float* W1s = W1 + 1024 * 1024;
  for (int h = 0; h < 4; ++h) {
    float sv[16];
#pragma unroll
    for (int s = 0; s < 16; ++s) sv[s] = st[h][s];
    float a0 = 0.f, a1 = 0.f, a2 = 0.f, a3 = 0.f;
    for (int j = t; j < 1024; j += 256) {
      float val = g_xw1[(size_t)bl * 1024 + j] + b1[j];
#pragma unroll
      for (int s = 0; s < 16; ++s) val += sv[s] * W1s[s * 1024 + j];
      float gg = 0.5f * val * (1.f + erff(val * 0.70710678118654752f));
      float4 w2 = *(const float4*)&W2[j * 4];
      a0 += gg * w2.x; a1 += gg * w2.y; a2 += gg * w2.z; a3 += gg * w2.w;
    }
#pragma unroll
    for (int off = 32; off; off >>= 1) {
      a0 += __shfl_xor(a0, off); a1 += __shfl_xor(a1, off);
      a2 += __shfl_xor(a2, off); a3 += __shfl_xor(a3, off);
    }
    int wv = t >> 6, lane = t & 63;
    if (lane == 0) { red[wv][0] = a0; red[wv][1] = a1; red[wv][2] = a2; red[wv][3] = a3; }
    __syncthreads();
    if (t == 0) {
      float lg[4];
#pragma unroll
      for (int m = 0; m < 4; ++m)
        lg[m] = red[0][m] + red[1][m] + red[2][m] + red[3][m] + b2[m] + base_bias[h * 4 + m];
      float lt = log_temp[h];
      float sp = (lt > 20.f) ? lt : log1pf(expf(lt));
      float inv = 1.f / (sp + 1e-4f);
      float z0 = lg[0] * inv, z1 = lg[1] * inv, z2 = lg[2] * inv, z3 = lg[3] * inv;
      float mx = fmaxf(fmaxf(z0, z1), fmaxf(z2, z3));
      float e0 = expf(z0 - mx), e1 = expf(z1 - mx), e2 = expf(z2 - mx), e3 = expf(z3 - mx);
      float si = 1.f / (e0 + e1 + e2 + e3);
      float p0 = e0 * si, p1 = e1 * si, p2 = e2 * si, p3 = e3 * si;
      p0 = fmaxf(p0, 0.05f); p1 = fmaxf(p1, 0.05f);
      float s2i = 1.f / (p0 + p1 + p2 + p3);
      p0 *= s2i; p1 *= s2i; p2 *= s2i; p3 *= s2i;
      p0 += 0.5f * sigmoidf(crl[h]);   // fold conv-residual into f_short coeff
      float4 pv; pv.x = p0; pv.y = p1; pv.z = p2; pv.w = p3;
      *(float4*)&g_p[((size_t)bl * 4 + h) * 4] = pv;
    }
    __syncthreads();
  }
}

// ================= mix 4 branches + RMSNorm =================
__global__ __launch_bounds__(256) void mix_rms_kernel(const float* __restrict__ rms_w) {
  int bl = blockIdx.x;
  int h = threadIdx.x >> 6, lane = threadIdx.x & 63;
  const float* pp = &g_p[((size_t)bl * 4 + h) * 4];
  float p0 = pp[0], p1 = pp[1], p2 = pp[2], p3 = pp[3];
  size_t base = (size_t)bl * ND + h * 256 + lane * 4;
  float4 a = *(const float4*)&g_fs[base];
  float4 bb = *(const float4*)&g_fl[base];
  float4 c = *(const float4*)&g_delta[base];
  float4 d = *(const float4*)&g_v[base];
  float o0 = p0 * a.x + p1 * bb.x + p2 * c.x + p3 * d.x;
  float o1 = p0 * a.y + p1 * bb.y + p2 * c.y + p3 * d.y;
  float o2 = p0 * a.z + p1 * bb.z + p2 * c.z + p3 * d.z;
  float o3 = p0 * a.w + p1 * bb.w + p2 * c.w + p3 * d.w;
  float s2 = o0 * o0 + o1 * o1 + o2 * o2 + o3 * o3;
#pragma unroll
  for (int off = 32; off; off >>= 1) s2 += __shfl_xor(s2, off);
  float rms = rsqrtf(s2 * (1.f / 256.f) + 1e-5f);
  float4 w4 = *(const float4*)&rms_w[lane * 4];
  float4 o;
  o.x = o0 * rms * w4.x; o.y = o1 * rms * w4.y; o.z = o2 * rms * w4.z; o.w = o3 * rms * w4.w;
  *(float4*)&g_omix[base] = o;
}

extern "C" void kernel_launch(void* const* d_in, const int* in_sizes, int n_in,
                              void* d_out, int out_size, void* d_ws, size_t ws_size,
                              hipStream_t stream) {
  const float* x = (const float*)d_in[0];
  const float* Wq = (const float*)d_in[1];
  const float* Wk = (const float*)d_in[2];
  const float* Wv = (const float*)d_in[3];
  const float* Wb = (const float*)d_in[4];
  const float* cq = (const float*)d_in[5];
  const float* ck = (const float*)d_in[6];
  const float* cv = (const float*)d_in[7];
  const float* firl = (const float*)d_in[8];
  const float* firs = (const float*)d_in[9];
  const float* W1 = (const float*)d_in[10];
  const float* b1 = (const float*)d_in[11];
  const float* W2 = (const float*)d_in[12];
  const float* b2 = (const float*)d_in[13];
  const float* ltp = (const float*)d_in[14];
  const float* bbs = (const float*)d_in[15];
  const float* crl = (const float*)d_in[16];
  const float* rw = (const float*)d_in[17];
  const float* Wo = (const float*)d_in[18];
  float* out = (float*)d_out;

  dim3 gemm_grid(8, 32), blk(256);
  sgemm_kernel<<<gemm_grid, blk, 0, stream>>>(x, Wq, nullptr, 0);
  sgemm_kernel<<<gemm_grid, blk, 0, stream>>>(x, Wk, nullptr, 1);
  sgemm_kernel<<<gemm_grid, blk, 0, stream>>>(x, Wv, nullptr, 2);
  conv_silu_kernel<<<BLDSZ / 256, blk, 0, stream>>>(cq, 0);
  conv_silu_kernel<<<BLDSZ / 256, blk, 0, stream>>>(ck, 1);
  conv_silu_kernel<<<BLDSZ / 256, blk, 0, stream>>>(cv, 2);
  beta_kernel<<<NBL, blk, 0, stream>>>(x, Wb);
  sgemm_kernel<<<gemm_grid, blk, 0, stream>>>(x, W1, nullptr, 3);  // x @ W1[:1024,:]
  delta_prep_kernel<<<NB * NH * NCHK, blk, 0, stream>>>();
  delta_scan_mfma<<<32, dim3(128), 0, stream>>>();
  fir_short_kernel<<<BLDSZ / 256, blk, 0, stream>>>(firs);
  fir_long_kernel<<<256, blk, 0, stream>>>(firl);
  stats_kernel<<<NBL * NH, dim3(64), 0, stream>>>();
  gate_kernel<<<NBL, blk, 0, stream>>>(W1, b1, W2, b2, ltp, bbs, crl);
  mix_rms_kernel<<<NBL, blk, 0, stream>>>(rw);
  sgemm_kernel<<<gemm_grid, blk, 0, stream>>>(nullptr, Wo, out, 4);
}

// Round 3
// 1179.585 us; speedup vs baseline: 1.7550x; 1.6916x over previous
//
#include <hip/hip_runtime.h>
#include <math.h>

// Problem constants
constexpr int NB = 2, NL = 2048, ND = 1024, NH = 4;
constexpr int NCHK = 64;            // L / 32
constexpr int NBL = NB * NL;        // 4096
#define BLDSZ (NB * NL * ND)        // 4194304

// ---- static device scratch ----
__device__ float g_qlin[BLDSZ];
__device__ float g_klin[BLDSZ];
__device__ float g_vlin[BLDSZ];
__device__ float g_q[BLDSZ];      // post conv+silu (fp32, prep input)
__device__ float g_k[BLDSZ];
__device__ float g_v[BLDSZ];
__device__ float g_delta[BLDSZ];  // (B,L,H,DV)
__device__ float g_fs[BLDSZ];
__device__ float g_fl[BLDSZ];
__device__ float g_xw1[BLDSZ];    // x @ W1[:1024,:]
__device__ float g_omix[BLDSZ];
__device__ float g_beta[NBL * NH];
__device__ float g_stats[NBL * NH * 16];
__device__ float g_p[NBL * NH * 4];

// ---- bf16 operand tensors for the MFMA scan (ushort = bf16 bits) ----
// chunk linear index cblk = bh*64 + n  (bh = b*4+h)
__device__ unsigned short g_qb[8 * 64 * 32 * 256];    // (cblk, row, dk) row-major
__device__ unsigned short g_wb[8 * 64 * 32 * 256];    // (cblk, row, dk)
__device__ unsigned short g_ktb[8 * 64 * 256 * 32];   // (cblk, dk, row)   k^T
__device__ unsigned short g_utb[8 * 64 * 256 * 32];   // (cblk, dv, row)   u^T
__device__ unsigned short g_attnb[8 * 64 * 32 * 32];  // (cblk, r, s)

__device__ __forceinline__ float sigmoidf(float x) { return 1.f / (1.f + expf(-x)); }

__device__ __forceinline__ unsigned short f2bf(float f) {
  union { float f; unsigned int u; } v; v.f = f;
  unsigned int r = v.u + 0x7FFFu + ((v.u >> 16) & 1u);   // RNE
  return (unsigned short)(r >> 16);
}
__device__ __forceinline__ float bf2f(unsigned int bits16) {
  union { unsigned int u; float f; } v; v.u = bits16 << 16; return v.f;
}
__device__ __forceinline__ unsigned int packbf(float a, float b) {
  return (unsigned int)f2bf(a) | ((unsigned int)f2bf(b) << 16);
}

typedef __attribute__((ext_vector_type(8))) short short8v;   // 8 bf16 (4 VGPR)
typedef __attribute__((ext_vector_type(16))) float f32x16;   // MFMA 32x32 accum

// ================= SGEMM: C[4096,1024] = A[4096,1024] * B[1024,1024] =================
__global__ __launch_bounds__(256) void sgemm_kernel(const float* __restrict__ Aext,
                                                    const float* __restrict__ Bw,
                                                    float* __restrict__ Cext, int sel) {
  __shared__ float As[16][132];
  __shared__ float Bs[16][132];
  const float* A = (sel == 4) ? g_omix : Aext;
  float* C;
  if (sel == 0) C = g_qlin;
  else if (sel == 1) C = g_klin;
  else if (sel == 2) C = g_vlin;
  else if (sel == 3) C = g_xw1;
  else C = Cext;

  const int t = threadIdx.x;
  const int tx = t & 15, ty = t >> 4;
  const int n0 = blockIdx.x * 128, m0 = blockIdx.y * 128;
  float acc[8][8];
#pragma unroll
  for (int i = 0; i < 8; ++i)
#pragma unroll
    for (int j = 0; j < 8; ++j) acc[i][j] = 0.f;

  for (int k0 = 0; k0 < 1024; k0 += 16) {
#pragma unroll
    for (int i = 0; i < 2; ++i) {
      int j = t + i * 256;
      int m = j >> 2, k4 = (j & 3) << 2;
      float4 av = *(const float4*)&A[(size_t)(m0 + m) * 1024 + k0 + k4];
      As[k4 + 0][m] = av.x; As[k4 + 1][m] = av.y; As[k4 + 2][m] = av.z; As[k4 + 3][m] = av.w;
    }
#pragma unroll
    for (int i = 0; i < 2; ++i) {
      int j = t + i * 256;
      int kk = j >> 5, n4 = (j & 31) << 2;
      *(float4*)&Bs[kk][n4] = *(const float4*)&Bw[(size_t)(k0 + kk) * 1024 + n0 + n4];
    }
    __syncthreads();
#pragma unroll
    for (int kk = 0; kk < 16; ++kk) {
      float4 a0 = *(const float4*)&As[kk][ty * 8];
      float4 a1 = *(const float4*)&As[kk][ty * 8 + 4];
      float4 b0 = *(const float4*)&Bs[kk][tx * 4];
      float4 b1 = *(const float4*)&Bs[kk][64 + tx * 4];
      float av[8] = {a0.x, a0.y, a0.z, a0.w, a1.x, a1.y, a1.z, a1.w};
      float bv[8] = {b0.x, b0.y, b0.z, b0.w, b1.x, b1.y, b1.z, b1.w};
#pragma unroll
      for (int i = 0; i < 8; ++i)
#pragma unroll
        for (int j = 0; j < 8; ++j) acc[i][j] += av[i] * bv[j];
    }
    __syncthreads();
  }
#pragma unroll
  for (int i = 0; i < 8; ++i) {
    size_t row = (size_t)(m0 + ty * 8 + i) * 1024 + n0;
    float4 r0, r1;
    r0.x = acc[i][0]; r0.y = acc[i][1]; r0.z = acc[i][2]; r0.w = acc[i][3];
    r1.x = acc[i][4]; r1.y = acc[i][5]; r1.z = acc[i][6]; r1.w = acc[i][7];
    *(float4*)&C[row + tx * 4] = r0;
    *(float4*)&C[row + 64 + tx * 4] = r1;
  }
}

// ================= causal depthwise conv (K=4) + SiLU =================
__global__ __launch_bounds__(256) void conv_silu_kernel(const float* __restrict__ cw, int sel) {
  const float* in = (sel == 0) ? g_qlin : (sel == 1) ? g_klin : g_vlin;
  float* out = (sel == 0) ? g_q : (sel == 1) ? g_k : g_v;
  int idx = blockIdx.x * 256 + threadIdx.x;
  int c = idx & (ND - 1);
  int bl = idx >> 10;
  int l = bl & (NL - 1);
  float w0 = cw[c * 4 + 0], w1 = cw[c * 4 + 1], w2 = cw[c * 4 + 2], w3 = cw[c * 4 + 3];
  float acc = w3 * in[(size_t)bl * ND + c];
  if (l >= 1) acc += w2 * in[(size_t)(bl - 1) * ND + c];
  if (l >= 2) acc += w1 * in[(size_t)(bl - 2) * ND + c];
  if (l >= 3) acc += w0 * in[(size_t)(bl - 3) * ND + c];
  out[idx] = acc * sigmoidf(acc);
}

// ================= beta = sigmoid(x @ Wb) =================
__global__ __launch_bounds__(256) void beta_kernel(const float* __restrict__ x,
                                                   const float* __restrict__ Wb) {
  int bl = blockIdx.x;
  int h = threadIdx.x >> 6, lane = threadIdx.x & 63;
  const float* xr = x + (size_t)bl * ND;
  float acc = 0.f;
  for (int d = lane; d < ND; d += 64) acc += xr[d] * Wb[d * 4 + h];
#pragma unroll
  for (int off = 32; off; off >>= 1) acc += __shfl_xor(acc, off);
  if (lane == 0) g_beta[bl * 4 + h] = sigmoidf(acc);
}

// ================= FIR short (K=5) =================
__global__ __launch_bounds__(256) void fir_short_kernel(const float* __restrict__ filt) {
  int idx = blockIdx.x * 256 + threadIdx.x;
  int c = idx & (ND - 1);
  int bl = idx >> 10;
  int l = bl & (NL - 1);
  const float* fp = filt + c * 5;
  float acc = 0.f;
#pragma unroll
  for (int tap = 0; tap < 5; ++tap) {
    int ls = l + tap - 4;
    if (ls >= 0) acc += fp[tap] * g_v[(size_t)(bl + tap - 4) * ND + c];
  }
  g_fs[idx] = acc;
}

// ================= FIR long (K=64) — register filter + unrolled scatter =================
// grid: ((b*64 + lb)*4 + cbk) = 512 blocks; thread owns channel c, 32 outputs.
__global__ __launch_bounds__(256) void fir_long_kernel(const float* __restrict__ filt) {
  int blk = blockIdx.x;
  int cbk = blk & 3, lb = (blk >> 2) & 63, b = blk >> 8;
  int t = threadIdx.x;
  int c = cbk * 256 + t;
  float ff[64];
#pragma unroll
  for (int i = 0; i < 16; ++i)
    *(float4*)&ff[i * 4] = *(const float4*)&filt[(size_t)c * 64 + i * 4];
  float acc[32];
#pragma unroll
  for (int i = 0; i < 32; ++i) acc[i] = 0.f;
  const float* vb = g_v + (size_t)b * NL * ND + c;
  const int l0 = lb * 32;
  // acc[li] = sum_tap ff[tap] * v[l0+li+tap-63]; d = li+tap in [0,94]
#pragma unroll
  for (int d = 0; d < 95; ++d) {
    int lr = l0 - 63 + d;
    float vv = (lr >= 0) ? vb[(size_t)lr * ND] : 0.f;
    const int lo = (d > 63) ? (d - 63) : 0;
    const int hi = (d < 31) ? d : 31;
#pragma unroll
    for (int li = lo; li <= hi; ++li) acc[li] += ff[d - li] * vv;
  }
  float* ob = g_fl + ((size_t)(b * NL + l0)) * ND + c;
#pragma unroll
  for (int li = 0; li < 32; ++li) ob[(size_t)li * ND] = acc[li];
}

// ================= delta-rule chunk prep =================
__global__ __launch_bounds__(256) void delta_prep_kernel() {
  __shared__ float X[32][260];
  __shared__ float Y[32][260];
  __shared__ float Am[32][33];
  __shared__ float Tm[32][33];
  __shared__ float bet[32];
  int blk = blockIdx.x;                  // cblk = (b*4+h)*64 + n
  int n = blk & 63, h = (blk >> 6) & 3, b = blk >> 8;
  int t = threadIdx.x;
  size_t rowbase = (size_t)(b * NL + n * 32);

  // load q->X, k->Y
#pragma unroll
  for (int i = 0; i < 8; ++i) {
    int j = t + i * 256;
    int r = j >> 6, d4 = (j & 63) << 2;
    size_t gi = (rowbase + r) * ND + h * 256 + d4;
    *(float4*)&X[r][d4] = *(const float4*)&g_q[gi];
    *(float4*)&Y[r][d4] = *(const float4*)&g_k[gi];
  }
  if (t < 32) bet[t] = g_beta[(rowbase + t) * 4 + h];
  __syncthreads();

  // row l2norm (8 lanes per row), LDS only
  {
    int wv = t >> 6, lane = t & 63;
    int r = wv * 8 + (lane >> 3), sub = lane & 7;
    float sq = 0.f, sk = 0.f;
#pragma unroll
    for (int m4 = 0; m4 < 8; ++m4) {
      float4 a = *(const float4*)&X[r][sub * 32 + m4 * 4];
      float4 bb = *(const float4*)&Y[r][sub * 32 + m4 * 4];
      sq += a.x * a.x + a.y * a.y + a.z * a.z + a.w * a.w;
      sk += bb.x * bb.x + bb.y * bb.y + bb.z * bb.z + bb.w * bb.w;
    }
    sq += __shfl_xor(sq, 1); sq += __shfl_xor(sq, 2); sq += __shfl_xor(sq, 4);
    sk += __shfl_xor(sk, 1); sk += __shfl_xor(sk, 2); sk += __shfl_xor(sk, 4);
    float rq = rsqrtf(sq + 1e-6f), rk = rsqrtf(sk + 1e-6f);
#pragma unroll
    for (int m4 = 0; m4 < 8; ++m4) {
      float4 a = *(const float4*)&X[r][sub * 32 + m4 * 4];
      a.x *= rq; a.y *= rq; a.z *= rq; a.w *= rq;
      *(float4*)&X[r][sub * 32 + m4 * 4] = a;
      float4 bb = *(const float4*)&Y[r][sub * 32 + m4 * 4];
      bb.x *= rk; bb.y *= rk; bb.z *= rk; bb.w *= rk;
      *(float4*)&Y[r][sub * 32 + m4 * 4] = bb;
    }
  }
  __syncthreads();

  // attn = incl_lower(qn kn^T) -> bf16
#pragma unroll
  for (int i = 0; i < 4; ++i) {
    int pr = t + i * 256;
    int r = pr >> 5, s = pr & 31;
    float acc = 0.f;
    if (s <= r) {
#pragma unroll 16
      for (int d4 = 0; d4 < 64; ++d4) {
        float4 a = *(const float4*)&X[r][d4 * 4];
        float4 bb = *(const float4*)&Y[s][d4 * 4];
        acc += a.x * bb.x + a.y * bb.y + a.z * bb.z + a.w * bb.w;
      }
    }
    g_attnb[(size_t)blk * 1024 + r * 32 + s] = f2bf(acc);
  }

  // qn -> g_qb (row-major); kn -> g_ktb (transposed)
  {
#pragma unroll 8
    for (int r = 0; r < 32; ++r)
      g_qb[((size_t)blk * 32 + r) * 256 + t] = f2bf(X[r][t]);
#pragma unroll
    for (int r8 = 0; r8 < 4; ++r8) {
      uint4 v;
      v.x = packbf(Y[r8 * 8 + 0][t], Y[r8 * 8 + 1][t]);
      v.y = packbf(Y[r8 * 8 + 2][t], Y[r8 * 8 + 3][t]);
      v.z = packbf(Y[r8 * 8 + 4][t], Y[r8 * 8 + 5][t]);
      v.w = packbf(Y[r8 * 8 + 6][t], Y[r8 * 8 + 7][t]);
      *(uint4*)&g_ktb[((size_t)blk * 256 + t) * 32 + r8 * 8] = v;
    }
  }
  __syncthreads();

  // X <- k_beta
#pragma unroll
  for (int i = 0; i < 8; ++i) {
    int j = t + i * 256;
    int r = j >> 6, d4 = (j & 63) << 2;
    float be = bet[r];
    float4 bb = *(const float4*)&Y[r][d4];
    bb.x *= be; bb.y *= be; bb.z *= be; bb.w *= be;
    *(float4*)&X[r][d4] = bb;
  }
  __syncthreads();

  // A = strict_lower(kb kn^T)
#pragma unroll
  for (int i = 0; i < 4; ++i) {
    int pr = t + i * 256;
    int r = pr >> 5, s = pr & 31;
    float acc = 0.f;
    if (s < r) {
#pragma unroll 16
      for (int d4 = 0; d4 < 64; ++d4) {
        float4 a = *(const float4*)&X[r][d4 * 4];
        float4 bb = *(const float4*)&Y[s][d4 * 4];
        acc += a.x * bb.x + a.y * bb.y + a.z * bb.z + a.w * bb.w;
      }
    }
    Am[r][s] = acc;
  }
  __syncthreads();

  // T = (I+A)^-1 forward substitution (lane j owns column j)
  if (t < 32) {
    int j = t;
    for (int i = 0; i < 32; ++i) {
      float a = (i == j) ? 1.f : 0.f;
      for (int m = j; m < i; ++m) a -= Am[i][m] * Tm[m][j];
      Tm[i][j] = a;
    }
  }
  __syncthreads();

  // w = T @ kb -> g_wb row-major bf16
  {
    float acc[32];
#pragma unroll
    for (int r = 0; r < 32; ++r) acc[r] = 0.f;
#pragma unroll
    for (int m = 0; m < 32; ++m) {
      float xv = X[m][t];
#pragma unroll
      for (int r = m; r < 32; ++r) acc[r] += Tm[r][m] * xv;
    }
#pragma unroll 8
    for (int r = 0; r < 32; ++r)
      g_wb[((size_t)blk * 32 + r) * 256 + t] = f2bf(acc[r]);
  }
  // Y <- v*beta
#pragma unroll
  for (int i = 0; i < 8; ++i) {
    int j = t + i * 256;
    int r = j >> 6, d4 = (j & 63) << 2;
    size_t gi = (rowbase + r) * ND + h * 256 + d4;
    float be = bet[r];
    float4 vv = *(const float4*)&g_v[gi];
    vv.x *= be; vv.y *= be; vv.z *= be; vv.w *= be;
    *(float4*)&Y[r][d4] = vv;
  }
  __syncthreads();

  // u = T @ vb -> g_utb transposed bf16
  {
    float acc[32];
#pragma unroll
    for (int r = 0; r < 32; ++r) acc[r] = 0.f;
#pragma unroll
    for (int m = 0; m < 32; ++m) {
      float yv = Y[m][t];
#pragma unroll
      for (int r = m; r < 32; ++r) acc[r] += Tm[r][m] * yv;
    }
#pragma unroll
    for (int r8 = 0; r8 < 4; ++r8) {
      uint4 v;
      v.x = packbf(acc[r8 * 8 + 0], acc[r8 * 8 + 1]);
      v.y = packbf(acc[r8 * 8 + 2], acc[r8 * 8 + 3]);
      v.z = packbf(acc[r8 * 8 + 4], acc[r8 * 8 + 5]);
      v.w = packbf(acc[r8 * 8 + 6], acc[r8 * 8 + 7]);
      *(uint4*)&g_utb[((size_t)blk * 256 + t) * 32 + r8 * 8] = v;
    }
  }
}

// ================= delta-rule scan — LDS-free, 1 wave per chain =================
// grid: 64 blocks = bh(8) * dv-slice(8, 32 cols); block = 1 wave (64 thr).
// S slice (256dk x 32dv) lives in 8 f32x16 MFMA accumulators for all 64 chunks.
// C-layout (verified): col = lane&31, row = (e&3) + 8*(e>>2) + 4*(lane>>5).
// C->B-frag conversion in-register: pack bf16 pairs, 4x shfl_xor(32), selects.
__global__ __launch_bounds__(64) void delta_scan_mfma() {
  const int blk = blockIdx.x;
  const int q = blk & 7, bh = blk >> 3;
  const int b = bh >> 2, h = bh & 3;
  const int lane = threadIdx.x;
  const int l31 = lane & 31, lhi = lane >> 5;

  f32x16 Sacc[8];
#pragma unroll
  for (int st = 0; st < 8; ++st)
#pragma unroll
    for (int e = 0; e < 16; ++e) Sacc[st][e] = 0.f;

  const unsigned short* wb = g_wb + (size_t)bh * 64 * 8192;
  const unsigned short* qb = g_qb + (size_t)bh * 64 * 8192;
  const unsigned short* ktb = g_ktb + (size_t)bh * 64 * 8192;
  const unsigned short* utb = g_utb + (size_t)bh * 64 * 8192;
  const unsigned short* ab = g_attnb + (size_t)bh * 64 * 1024;

  for (int n = 0; n < 64; ++n) {
    const unsigned short* wp = wb + n * 8192 + l31 * 256 + lhi * 8;
    const unsigned short* qp = qb + n * 8192 + l31 * 256 + lhi * 8;
    f32x16 wuA, wuB, ooA, ooB;
#pragma unroll
    for (int e = 0; e < 16; ++e) { wuA[e] = 0.f; wuB[e] = 0.f; ooA[e] = 0.f; ooB[e] = 0.f; }

    // ---- phase 1: wu = w@S, oo = q@S ----
#pragma unroll
    for (int st = 0; st < 8; ++st) {
      unsigned int P[8];
#pragma unroll
      for (int m = 0; m < 8; ++m) P[m] = packbf(Sacc[st][2 * m], Sacc[st][2 * m + 1]);
      unsigned int s1 = (unsigned int)__shfl_xor((int)(lhi ? P[0] : P[2]), 32);
      unsigned int s2 = (unsigned int)__shfl_xor((int)(lhi ? P[1] : P[3]), 32);
      unsigned int s3 = (unsigned int)__shfl_xor((int)(lhi ? P[4] : P[6]), 32);
      unsigned int s4 = (unsigned int)__shfl_xor((int)(lhi ? P[5] : P[7]), 32);
      unsigned int f0[4] = { lhi ? s1 : P[0], lhi ? s2 : P[1], lhi ? P[2] : s1, lhi ? P[3] : s2 };
      unsigned int f1[4] = { lhi ? s3 : P[4], lhi ? s4 : P[5], lhi ? P[6] : s3, lhi ? P[7] : s4 };
      short8v fb0 = *(short8v*)f0;
      short8v fb1 = *(short8v*)f1;
      short8v wa0 = *(const short8v*)(wp + st * 32);
      short8v wa1 = *(const short8v*)(wp + st * 32 + 16);
      short8v qa0 = *(const short8v*)(qp + st * 32);
      short8v qa1 = *(const short8v*)(qp + st * 32 + 16);
      if (st & 1) {
        wuB = __builtin_amdgcn_mfma_f32_32x32x16_bf16(wa0, fb0, wuB, 0, 0, 0);
        wuB = __builtin_amdgcn_mfma_f32_32x32x16_bf16(wa1, fb1, wuB, 0, 0, 0);
        ooB = __builtin_amdgcn_mfma_f32_32x32x16_bf16(qa0, fb0, ooB, 0, 0, 0);
        ooB = __builtin_amdgcn_mfma_f32_32x32x16_bf16(qa1, fb1, ooB, 0, 0, 0);
      } else {
        wuA = __builtin_amdgcn_mfma_f32_32x32x16_bf16(wa0, fb0, wuA, 0, 0, 0);
        wuA = __builtin_amdgcn_mfma_f32_32x32x16_bf16(wa1, fb1, wuA, 0, 0, 0);
        ooA = __builtin_amdgcn_mfma_f32_32x32x16_bf16(qa0, fb0, ooA, 0, 0, 0);
        ooA = __builtin_amdgcn_mfma_f32_32x32x16_bf16(qa1, fb1, ooA, 0, 0, 0);
      }
    }

    // ---- phase 2: u_t = u - wu (C-layout), convert to B-frags ----
    float ut[16];
    const unsigned short* up = utb + n * 8192 + (q * 32 + l31) * 32 + 4 * lhi;
#pragma unroll
    for (int g = 0; g < 4; ++g) {
      uint2 uu = *(const uint2*)(up + 8 * g);
      ut[4 * g + 0] = bf2f(uu.x & 0xffffu) - wuA[4 * g + 0] - wuB[4 * g + 0];
      ut[4 * g + 1] = bf2f(uu.x >> 16)     - wuA[4 * g + 1] - wuB[4 * g + 1];
      ut[4 * g + 2] = bf2f(uu.y & 0xffffu) - wuA[4 * g + 2] - wuB[4 * g + 2];
      ut[4 * g + 3] = bf2f(uu.y >> 16)     - wuA[4 * g + 3] - wuB[4 * g + 3];
    }
    short8v utk0, utk1;
    {
      unsigned int P[8];
#pragma unroll
      for (int m = 0; m < 8; ++m) P[m] = packbf(ut[2 * m], ut[2 * m + 1]);
      unsigned int s1 = (unsigned int)__shfl_xor((int)(lhi ? P[0] : P[2]), 32);
      unsigned int s2 = (unsigned int)__shfl_xor((int)(lhi ? P[1] : P[3]), 32);
      unsigned int s3 = (unsigned int)__shfl_xor((int)(lhi ? P[4] : P[6]), 32);
      unsigned int s4 = (unsigned int)__shfl_xor((int)(lhi ? P[5] : P[7]), 32);
      unsigned int f0[4] = { lhi ? s1 : P[0], lhi ? s2 : P[1], lhi ? P[2] : s1, lhi ? P[3] : s2 };
      unsigned int f1[4] = { lhi ? s3 : P[4], lhi ? s4 : P[5], lhi ? P[6] : s3, lhi ? P[7] : s4 };
      utk0 = *(short8v*)f0;
      utk1 = *(short8v*)f1;
    }

    // ---- phase 3: oo += attn @ u_t ; S += k^T @ u_t ----
    const unsigned short* ap = ab + n * 1024 + l31 * 32 + lhi * 8;
    {
      short8v aa0 = *(const short8v*)ap;
      short8v aa1 = *(const short8v*)(ap + 16);
      ooA = __builtin_amdgcn_mfma_f32_32x32x16_bf16(aa0, utk0, ooA, 0, 0, 0);
      ooB = __builtin_amdgcn_mfma_f32_32x32x16_bf16(aa1, utk1, ooB, 0, 0, 0);
    }
    const unsigned short* kp = ktb + n * 8192 + l31 * 32 + lhi * 8;
#pragma unroll
    for (int st = 0; st < 8; ++st) {
      short8v ka0 = *(const short8v*)(kp + st * 1024);
      short8v ka1 = *(const short8v*)(kp + st * 1024 + 16);
      Sacc[st] = __builtin_amdgcn_mfma_f32_32x32x16_bf16(ka0, utk0, Sacc[st], 0, 0, 0);
      Sacc[st] = __builtin_amdgcn_mfma_f32_32x32x16_bf16(ka1, utk1, Sacc[st], 0, 0, 0);
    }

    // ---- write delta (fp32) ----
    size_t obase = ((size_t)(b * NL + n * 32)) * ND + h * 256 + q * 32 + l31;
#pragma unroll
    for (int e = 0; e < 16; ++e) {
      int row = (e & 3) + 8 * (e >> 2) + 4 * lhi;
      g_delta[obase + (size_t)row * ND] = ooA[e] + ooB[e];
    }
  }
}

// ================= per-branch stats =================
__global__ __launch_bounds__(64) void stats_kernel() {
  int g = blockIdx.x;               // bl*4 + h
  int h = g & 3, bl = g >> 2;
  int lane = threadIdx.x;
  size_t base = (size_t)bl * ND + h * 256 + lane * 4;
#pragma unroll
  for (int br = 0; br < 4; ++br) {
    const float* p = (br == 0) ? g_fs : (br == 1) ? g_fl : (br == 2) ? g_delta : g_v;
    float4 x4 = *(const float4*)&p[base];
    float s = x4.x + x4.y + x4.z + x4.w;
    float s2 = x4.x * x4.x + x4.y * x4.y + x4.z * x4.z + x4.w * x4.w;
    float sa = fabsf(x4.x) + fabsf(x4.y) + fabsf(x4.z) + fabsf(x4.w);
#pragma unroll
    for (int off = 32; off; off >>= 1) {
      s += __shfl_xor(s, off);
      s2 += __shfl_xor(s2, off);
      sa += __shfl_xor(sa, off);
    }
    if (lane == 0) {
      float mean = s * (1.f / 256.f);
      float4 o;
      o.x = mean;
      o.y = s2 * (1.f / 256.f) - mean * mean;
      o.z = sa * (1.f / 256.f);
      o.w = sqrtf(s2);
      *(float4*)&g_stats[(size_t)g * 16 + br * 4] = o;
    }
  }
}

// ================= gate MLP tail + softmax/floor =================
__global__ __launch_bounds__(256) void gate_kernel(const float* __restrict__ W1,
                                                   const float* __restrict__ b1,
                                                   const float* __restrict__ W2,
                                                   const float* __restrict__ b2,
                                                   const float* __restrict__ log_temp,
                                                   const float* __restrict__ base_bias,
                                                   const float* __restrict__ crl) {
  __shared__ float st[4][16];
  __shared__ float red[4][4];
  int bl = blockIdx.x, t = threadIdx.x;
  if (t < 64) (&st[0][0])[t] = g_stats[(size_t)bl * 64 + t];
  __syncthreads();
  const float* W1s = W1 + 1024 * 1024;
  for (int h = 0; h < 4; ++h) {
    float sv[16];
#pragma unroll
    for (int s = 0; s < 16; ++s) sv[s] = st[h][s];
    float a0 = 0.f, a1 = 0.f, a2 = 0.f, a3 = 0.f;
    for (int j = t; j < 1024; j += 256) {
      float val = g_xw1[(size_t)bl * 1024 + j] + b1[j];
#pragma unroll
      for (int s = 0; s < 16; ++s) val += sv[s] * W1s[s * 1024 + j];
      float gg = 0.5f * val * (1.f + erff(val * 0.70710678118654752f));
      float4 w2 = *(const float4*)&W2[j * 4];
      a0 += gg * w2.x; a1 += gg * w2.y; a2 += gg * w2.z; a3 += gg * w2.w;
    }
#pragma unroll
    for (int off = 32; off; off >>= 1) {
      a0 += __shfl_xor(a0, off); a1 += __shfl_xor(a1, off);
      a2 += __shfl_xor(a2, off); a3 += __shfl_xor(a3, off);
    }
    int wv = t >> 6, lane = t & 63;
    if (lane == 0) { red[wv][0] = a0; red[wv][1] = a1; red[wv][2] = a2; red[wv][3] = a3; }
    __syncthreads();
    if (t == 0) {
      float lg[4];
#pragma unroll
      for (int m = 0; m < 4; ++m)
        lg[m] = red[0][m] + red[1][m] + red[2][m] + red[3][m] + b2[m] + base_bias[h * 4 + m];
      float lt = log_temp[h];
      float sp = (lt > 20.f) ? lt : log1pf(expf(lt));
      float inv = 1.f / (sp + 1e-4f);
      float z0 = lg[0] * inv, z1 = lg[1] * inv, z2 = lg[2] * inv, z3 = lg[3] * inv;
      float mx = fmaxf(fmaxf(z0, z1), fmaxf(z2, z3));
      float e0 = expf(z0 - mx), e1 = expf(z1 - mx), e2 = expf(z2 - mx), e3 = expf(z3 - mx);
      float si = 1.f / (e0 + e1 + e2 + e3);
      float p0 = e0 * si, p1 = e1 * si, p2 = e2 * si, p3 = e3 * si;
      p0 = fmaxf(p0, 0.05f); p1 = fmaxf(p1, 0.05f);
      float s2i = 1.f / (p0 + p1 + p2 + p3);
      p0 *= s2i; p1 *= s2i; p2 *= s2i; p3 *= s2i;
      p0 += 0.5f * sigmoidf(crl[h]);   // fold conv-residual into f_short coeff
      float4 pv; pv.x = p0; pv.y = p1; pv.z = p2; pv.w = p3;
      *(float4*)&g_p[((size_t)bl * 4 + h) * 4] = pv;
    }
    __syncthreads();
  }
}

// ================= mix 4 branches + RMSNorm =================
__global__ __launch_bounds__(256) void mix_rms_kernel(const float* __restrict__ rms_w) {
  int bl = blockIdx.x;
  int h = threadIdx.x >> 6, lane = threadIdx.x & 63;
  const float* pp = &g_p[((size_t)bl * 4 + h) * 4];
  float p0 = pp[0], p1 = pp[1], p2 = pp[2], p3 = pp[3];
  size_t base = (size_t)bl * ND + h * 256 + lane * 4;
  float4 a = *(const float4*)&g_fs[base];
  float4 bb = *(const float4*)&g_fl[base];
  float4 c = *(const float4*)&g_delta[base];
  float4 d = *(const float4*)&g_v[base];
  float o0 = p0 * a.x + p1 * bb.x + p2 * c.x + p3 * d.x;
  float o1 = p0 * a.y + p1 * bb.y + p2 * c.y + p3 * d.y;
  float o2 = p0 * a.z + p1 * bb.z + p2 * c.z + p3 * d.z;
  float o3 = p0 * a.w + p1 * bb.w + p2 * c.w + p3 * d.w;
  float s2 = o0 * o0 + o1 * o1 + o2 * o2 + o3 * o3;
#pragma unroll
  for (int off = 32; off; off >>= 1) s2 += __shfl_xor(s2, off);
  float rms = rsqrtf(s2 * (1.f / 256.f) + 1e-5f);
  float4 w4 = *(const float4*)&rms_w[lane * 4];
  float4 o;
  o.x = o0 * rms * w4.x; o.y = o1 * rms * w4.y; o.z = o2 * rms * w4.z; o.w = o3 * rms * w4.w;
  *(float4*)&g_omix[base] = o;
}

extern "C" void kernel_launch(void* const* d_in, const int* in_sizes, int n_in,
                              void* d_out, int out_size, void* d_ws, size_t ws_size,
                              hipStream_t stream) {
  const float* x = (const float*)d_in[0];
  const float* Wq = (const float*)d_in[1];
  const float* Wk = (const float*)d_in[2];
  const float* Wv = (const float*)d_in[3];
  const float* Wb = (const float*)d_in[4];
  const float* cq = (const float*)d_in[5];
  const float* ck = (const float*)d_in[6];
  const float* cv = (const float*)d_in[7];
  const float* firl = (const float*)d_in[8];
  const float* firs = (const float*)d_in[9];
  const float* W1 = (const float*)d_in[10];
  const float* b1 = (const float*)d_in[11];
  const float* W2 = (const float*)d_in[12];
  const float* b2 = (const float*)d_in[13];
  const float* ltp = (const float*)d_in[14];
  const float* bbs = (const float*)d_in[15];
  const float* crl = (const float*)d_in[16];
  const float* rw = (const float*)d_in[17];
  const float* Wo = (const float*)d_in[18];
  float* out = (float*)d_out;

  dim3 gemm_grid(8, 32), blk(256);
  sgemm_kernel<<<gemm_grid, blk, 0, stream>>>(x, Wq, nullptr, 0);
  sgemm_kernel<<<gemm_grid, blk, 0, stream>>>(x, Wk, nullptr, 1);
  sgemm_kernel<<<gemm_grid, blk, 0, stream>>>(x, Wv, nullptr, 2);
  conv_silu_kernel<<<BLDSZ / 256, blk, 0, stream>>>(cq, 0);
  conv_silu_kernel<<<BLDSZ / 256, blk, 0, stream>>>(ck, 1);
  conv_silu_kernel<<<BLDSZ / 256, blk, 0, stream>>>(cv, 2);
  beta_kernel<<<NBL, blk, 0, stream>>>(x, Wb);
  sgemm_kernel<<<gemm_grid, blk, 0, stream>>>(x, W1, nullptr, 3);  // x @ W1[:1024,:]
  delta_prep_kernel<<<NB * NH * NCHK, blk, 0, stream>>>();
  delta_scan_mfma<<<64, dim3(64), 0, stream>>>();
  fir_short_kernel<<<BLDSZ / 256, blk, 0, stream>>>(firs);
  fir_long_kernel<<<512, blk, 0, stream>>>(firl);
  stats_kernel<<<NBL * NH, dim3(64), 0, stream>>>();
  gate_kernel<<<NBL, blk, 0, stream>>>(W1, b1, W2, b2, ltp, bbs, crl);
  mix_rms_kernel<<<NBL, blk, 0, stream>>>(rw);
  sgemm_kernel<<<gemm_grid, blk, 0, stream>>>(nullptr, Wo, out, 4);
}